// Round 4
// baseline (3688.207 us; speedup 1.0000x reference)
//
#include <hip/hip_runtime.h>

#define NN 50000
#define NE 800000
#define IN_DIM 16
#define H 32
#define EDGE_DIM 4
#define T_STEPS 4

#define GROUPS 8            // 32-lane channel groups per 256-thread block
#define NPASS 4             // nodes handled sequentially per group
#define NODES_PER_BLK (GROUPS * NPASS)   // 32
#define NBLK ((NN + NODES_PER_BLK - 1) / NODES_PER_BLK)

// ---------------- embedding: h0 = inputs @ W_emb ----------------
__global__ __launch_bounds__(256) void embed_kernel(const float* __restrict__ inputs,
                                                    const float* __restrict__ W_emb,
                                                    float* __restrict__ h) {
    __shared__ float W[IN_DIM * H];
    for (int i = threadIdx.x; i < IN_DIM * H; i += 256) W[i] = W_emb[i];
    __syncthreads();
    int idx = blockIdx.x * 256 + threadIdx.x;
    if (idx >= NN * H) return;
    int n = idx >> 5, j = idx & 31;
    const float* xr = inputs + n * IN_DIM;
    float acc = 0.f;
#pragma unroll
    for (int k = 0; k < IN_DIM; ++k) acc += xr[k] * W[k * H + j];
    h[idx] = acc;
}

// ---------------- CSR build ----------------
__global__ __launch_bounds__(256) void hist_kernel(const int* __restrict__ dst, int* __restrict__ deg) {
    int e = blockIdx.x * 256 + threadIdx.x;
    if (e < NE) atomicAdd(&deg[dst[e]], 1);
}

#define SCAN_CHUNK 49
__global__ __launch_bounds__(1024) void scan_kernel(const int* __restrict__ deg, int* __restrict__ row_ptr) {
    __shared__ int part[1024];
    int tid = threadIdx.x;
    int start = tid * SCAN_CHUNK;
    int s = 0;
    for (int i = 0; i < SCAN_CHUNK; ++i) {
        int idx = start + i;
        if (idx < NN) s += deg[idx];
    }
    part[tid] = s;
    __syncthreads();
    for (int off = 1; off < 1024; off <<= 1) {
        int v = (tid >= off) ? part[tid - off] : 0;
        __syncthreads();
        part[tid] += v;
        __syncthreads();
    }
    int run = (tid == 0) ? 0 : part[tid - 1];
    for (int i = 0; i < SCAN_CHUNK; ++i) {
        int idx = start + i;
        if (idx <= NN) row_ptr[idx] = run;
        if (idx < NN) run += deg[idx];
    }
}

__global__ __launch_bounds__(256) void scatter_kernel(const int* __restrict__ src, const int* __restrict__ dst,
                                                      const int* __restrict__ row_ptr, int* __restrict__ cnt,
                                                      int* __restrict__ src_sorted, int* __restrict__ eid_sorted) {
    int e = blockIdx.x * 256 + threadIdx.x;
    if (e >= NE) return;
    int d = dst[e];
    int pos = row_ptr[d] + atomicAdd(&cnt[d], 1);
    src_sorted[pos] = src[e];
    eid_sorted[pos] = e;
}

// ---------------- ef re-layout: ef_sorted[t][p][4] ----------------
__global__ __launch_bounds__(256) void ef_sort_kernel(const float* __restrict__ e_feats,
                                                      const int* __restrict__ eid_sorted,
                                                      float* __restrict__ ef_sorted) {
    int p = blockIdx.x * 256 + threadIdx.x;
    if (p >= NE) return;
    int e = eid_sorted[p];
    float buf[16];
    const float4* srcp = (const float4*)(e_feats + (size_t)e * (EDGE_DIM * T_STEPS));
#pragma unroll
    for (int q = 0; q < 4; ++q) {
        float4 v = srcp[q];
        buf[4 * q + 0] = v.x; buf[4 * q + 1] = v.y; buf[4 * q + 2] = v.z; buf[4 * q + 3] = v.w;
    }
#pragma unroll
    for (int t = 0; t < T_STEPS; ++t) {
        float4 o = make_float4(buf[t], buf[4 + t], buf[8 + t], buf[12 + t]);
        *(float4*)(ef_sorted + ((size_t)t * NE + p) * 4) = o;
    }
}

// ---------------- fused layer: node x channel threads, register-only ----------------
// thread (g,c): channel c of node n. Edge loop: broadcast-read h[src] row + ef row,
// dot36 with We column (in regs), relu-accumulate agg in a register.
// Node update: h/agg values exchanged via __shfl within the 32-lane group; Wn from L1.
__global__ __launch_bounds__(256) void layer_kernel(const float* __restrict__ h,
                                                    const float* __restrict__ ef_t,
                                                    const int* __restrict__ src_sorted,
                                                    const int* __restrict__ row_ptr,
                                                    const float* __restrict__ rain0,
                                                    const float* __restrict__ We,
                                                    const float* __restrict__ Wn,
                                                    const float* __restrict__ Wrain,
                                                    float* __restrict__ hnew,
                                                    float* __restrict__ out,
                                                    int t, int last) {
    int tid = threadIdx.x;
    int g = tid >> 5;          // group 0..7
    int c = tid & 31;          // channel
    int lbase = tid & 32;      // group base lane within the wave

    // cache We column c (36 regs); rows coalesced across c lanes
    float we[36];
#pragma unroll
    for (int k = 0; k < 36; ++k) we[k] = We[k * 32 + c];
    float wr = Wrain[c];

    int nb0 = blockIdx.x * NODES_PER_BLK + g * NPASS;

    for (int pass = 0; pass < NPASS; ++pass) {
        int n = nb0 + pass;
        if (n >= NN) break;
        int rb = row_ptr[n], re = row_ptr[n + 1];

        float acc = 0.f;
        for (int p = rb; p < re; ++p) {
            int s = src_sorted[p];                      // broadcast within group
            const float4* hr = (const float4*)(h + (size_t)s * H);
            float4 a0 = hr[0], a1 = hr[1], a2 = hr[2], a3 = hr[3];
            float4 a4 = hr[4], a5 = hr[5], a6 = hr[6], a7 = hr[7];
            float4 ev = *(const float4*)(ef_t + (size_t)p * 4);
            float m0 = a0.x * we[0]  + a0.y * we[1]  + a0.z * we[2]  + a0.w * we[3];
            float m1 = a1.x * we[4]  + a1.y * we[5]  + a1.z * we[6]  + a1.w * we[7];
            float m2 = a2.x * we[8]  + a2.y * we[9]  + a2.z * we[10] + a2.w * we[11];
            float m3 = a3.x * we[12] + a3.y * we[13] + a3.z * we[14] + a3.w * we[15];
            m0 += a4.x * we[16] + a4.y * we[17] + a4.z * we[18] + a4.w * we[19];
            m1 += a5.x * we[20] + a5.y * we[21] + a5.z * we[22] + a5.w * we[23];
            m2 += a6.x * we[24] + a6.y * we[25] + a6.z * we[26] + a6.w * we[27];
            m3 += a7.x * we[28] + a7.y * we[29] + a7.z * we[30] + a7.w * we[31];
            m0 += ev.x * we[32] + ev.y * we[33];
            m1 += ev.z * we[34] + ev.w * we[35];
            acc += fmaxf((m0 + m1) + (m2 + m3), 0.f);
        }

        // node update: acc2 = sum_k [h(n); agg(n); rain] [k] * Wn[k][c]
        float hval = h[(size_t)n * H + c];
        float rain = rain0[(size_t)n * T_STEPS + t];
        float acc2 = rain * Wn[64 * 32 + c];
#pragma unroll
        for (int k = 0; k < 32; ++k) {
            float xk = __shfl(hval, lbase + k, 64);
            acc2 += xk * Wn[k * 32 + c];
        }
#pragma unroll
        for (int k = 0; k < 32; ++k) {
            float ak = __shfl(acc, lbase + k, 64);
            acc2 += ak * Wn[(32 + k) * 32 + c];
        }
        float v = fmaxf(acc2, 0.f);
        hnew[(size_t)n * H + c] = v;
        if (last) {
            float rv = v * wr;
#pragma unroll
            for (int off = 16; off >= 1; off >>= 1) rv += __shfl_xor(rv, off, 64);
            if (c == 0) out[(size_t)n * T_STEPS + t] = rv;
        }
    }
}

extern "C" void kernel_launch(void* const* d_in, const int* in_sizes, int n_in,
                              void* d_out, int out_size, void* d_ws, size_t ws_size,
                              hipStream_t stream) {
    const float* inputs     = (const float*)d_in[0];
    const float* e_feats    = (const float*)d_in[1];
    const float* rain0      = (const float*)d_in[2];
    const float* W_emb      = (const float*)d_in[3];
    const float* W_edge_in  = (const float*)d_in[4];
    const float* W_node_in  = (const float*)d_in[5];
    const float* W_edge_out = (const float*)d_in[6];
    const float* W_node_out = (const float*)d_in[7];
    const float* W_rain     = (const float*)d_in[8];
    const int*   src        = (const int*)d_in[9];
    const int*   dst        = (const int*)d_in[10];
    float* out = (float*)d_out;

    // workspace layout (~76 MB)
    size_t fH = (size_t)NN * H;
    size_t fE = (size_t)NE * 4;
    float* h_a       = (float*)d_ws;
    float* h_b       = h_a + fH;
    float* ef_sorted = h_b + fH;                                   // T * NE * 4 floats
    int* row_ptr     = (int*)(ef_sorted + (size_t)T_STEPS * fE);   // NN+1
    int* deg         = row_ptr + (NN + 1);                         // NN
    int* cnt         = deg + NN;                                   // NN
    int* src_sorted  = cnt + NN;                                   // NE
    int* eid_sorted  = src_sorted + NE;                            // NE

    embed_kernel<<<(NN * H + 255) / 256, 256, 0, stream>>>(inputs, W_emb, h_a);

    // CSR build
    hipMemsetAsync(deg, 0, (size_t)2 * NN * sizeof(int), stream);  // deg + cnt contiguous
    hist_kernel<<<(NE + 255) / 256, 256, 0, stream>>>(dst, deg);
    scan_kernel<<<1, 1024, 0, stream>>>(deg, row_ptr);
    scatter_kernel<<<(NE + 255) / 256, 256, 0, stream>>>(src, dst, row_ptr, cnt, src_sorted, eid_sorted);
    ef_sort_kernel<<<(NE + 255) / 256, 256, 0, stream>>>(e_feats, eid_sorted, ef_sorted);

    float* hc = h_a;
    float* hn = h_b;
    for (int t = 0; t < T_STEPS; ++t) {
        const float* ef_t = ef_sorted + (size_t)t * fE;
        for (int s = 0; s < 3; ++s) {
            const float* We = (s < 2) ? (W_edge_in + (size_t)s * 36 * H) : W_edge_out;
            const float* Wn = (s < 2) ? (W_node_in + (size_t)s * 65 * H) : W_node_out;
            layer_kernel<<<NBLK, 256, 0, stream>>>(hc, ef_t, src_sorted, row_ptr, rain0,
                                                   We, Wn, W_rain, hn, out, t, (s == 2) ? 1 : 0);
            float* tmp = hc; hc = hn; hn = tmp;
        }
    }
}

// Round 5
// 3190.258 us; speedup vs baseline: 1.1561x; 1.1561x over previous
//
#include <hip/hip_runtime.h>

#define NN 50000
#define NE 800000
#define IN_DIM 16
#define H 32
#define EDGE_DIM 4
#define T_STEPS 4
#define NPB 32
#define NBLK ((NN + NPB - 1) / NPB)   // 1563

// ---------------- embedding: h0 = inputs @ W_emb ----------------
__global__ __launch_bounds__(256) void embed_kernel(const float* __restrict__ inputs,
                                                    const float* __restrict__ W_emb,
                                                    float* __restrict__ h) {
    __shared__ float W[IN_DIM * H];
    for (int i = threadIdx.x; i < IN_DIM * H; i += 256) W[i] = W_emb[i];
    __syncthreads();
    int idx = blockIdx.x * 256 + threadIdx.x;
    if (idx >= NN * H) return;
    int n = idx >> 5, j = idx & 31;
    const float* xr = inputs + n * IN_DIM;
    float acc = 0.f;
#pragma unroll
    for (int k = 0; k < IN_DIM; ++k) acc += xr[k] * W[k * H + j];
    h[idx] = acc;
}

// ---------------- CSR build ----------------
__global__ __launch_bounds__(256) void hist_kernel(const int* __restrict__ dst, int* __restrict__ deg) {
    int e = blockIdx.x * 256 + threadIdx.x;
    if (e < NE) atomicAdd(&deg[dst[e]], 1);
}

#define SCAN_CHUNK 49
__global__ __launch_bounds__(1024) void scan_kernel(const int* __restrict__ deg, int* __restrict__ row_ptr) {
    __shared__ int part[1024];
    int tid = threadIdx.x;
    int start = tid * SCAN_CHUNK;
    int s = 0;
    for (int i = 0; i < SCAN_CHUNK; ++i) {
        int idx = start + i;
        if (idx < NN) s += deg[idx];
    }
    part[tid] = s;
    __syncthreads();
    for (int off = 1; off < 1024; off <<= 1) {
        int v = (tid >= off) ? part[tid - off] : 0;
        __syncthreads();
        part[tid] += v;
        __syncthreads();
    }
    int run = (tid == 0) ? 0 : part[tid - 1];
    for (int i = 0; i < SCAN_CHUNK; ++i) {
        int idx = start + i;
        if (idx <= NN) row_ptr[idx] = run;
        if (idx < NN) run += deg[idx];
    }
}

__global__ __launch_bounds__(256) void scatter_kernel(const int* __restrict__ src, const int* __restrict__ dst,
                                                      const int* __restrict__ row_ptr, int* __restrict__ cnt,
                                                      int* __restrict__ src_sorted, int* __restrict__ dst_sorted,
                                                      int* __restrict__ eid_sorted) {
    int e = blockIdx.x * 256 + threadIdx.x;
    if (e >= NE) return;
    int d = dst[e];
    int pos = row_ptr[d] + atomicAdd(&cnt[d], 1);
    src_sorted[pos] = src[e];
    dst_sorted[pos] = d;
    eid_sorted[pos] = e;
}

// ---------------- ef re-layout: ef_sorted[t][p][4] ----------------
__global__ __launch_bounds__(256) void ef_sort_kernel(const float* __restrict__ e_feats,
                                                      const int* __restrict__ eid_sorted,
                                                      float* __restrict__ ef_sorted) {
    int p = blockIdx.x * 256 + threadIdx.x;
    if (p >= NE) return;
    int e = eid_sorted[p];
    float buf[16];
    const float4* srcp = (const float4*)(e_feats + (size_t)e * (EDGE_DIM * T_STEPS));
#pragma unroll
    for (int q = 0; q < 4; ++q) {
        float4 v = srcp[q];
        buf[4 * q + 0] = v.x; buf[4 * q + 1] = v.y; buf[4 * q + 2] = v.z; buf[4 * q + 3] = v.w;
    }
#pragma unroll
    for (int t = 0; t < T_STEPS; ++t) {
        float4 o = make_float4(buf[t], buf[4 + t], buf[8 + t], buf[12 + t]);
        *(float4*)(ef_sorted + ((size_t)t * NE + p) * 4) = o;
    }
}

// ---------------- fused layer ----------------
// Edge phase: thread owns 2 consecutive sorted edges; weights via uniform (SGPR) loads;
// aggregation via LDS float atomics into sagg. Node phase: 8-way k-split + LDS atomic combine.
__global__ __launch_bounds__(256, 4) void layer_kernel(const float* __restrict__ h,
                                                       const float* __restrict__ ef_t,
                                                       const int* __restrict__ src_sorted,
                                                       const int* __restrict__ dst_sorted,
                                                       const int* __restrict__ row_ptr,
                                                       const float* __restrict__ rain0,
                                                       const float* __restrict__ We,
                                                       const float* __restrict__ Wn,
                                                       const float* __restrict__ Wrain,
                                                       float* __restrict__ hnew,
                                                       float* __restrict__ out,
                                                       int t, int last) {
    __shared__ float sagg[NPB * 33];
    __shared__ float shl[NPB * 33];

    int tid = threadIdx.x;
    int nb0 = blockIdx.x * NPB;
    int nEnd = min(nb0 + NPB, NN);
    int nloc = nEnd - nb0;

    for (int i = tid; i < NPB * 33; i += 256) sagg[i] = 0.f;
    for (int i = tid; i < nloc * H; i += 256) {
        int g = i >> 5, c = i & 31;
        shl[g * 33 + c] = h[(size_t)(nb0 + g) * H + c];
    }
    int e0 = row_ptr[nb0], e1 = row_ptr[nEnd];
    __syncthreads();

    // -------- edge phase --------
    for (int p = e0 + tid * 2; p < e1; p += 512) {
        int has2 = (p + 1 < e1);
        int s0 = src_sorted[p];
        int s1 = has2 ? src_sorted[p + 1] : s0;
        int d0 = dst_sorted[p];
        int d1 = has2 ? dst_sorted[p + 1] : -1;

        const float4* r0 = (const float4*)(h + (size_t)s0 * H);
        const float4* r1 = (const float4*)(h + (size_t)s1 * H);

        float a0[32], a1[32];
#pragma unroll
        for (int j = 0; j < 32; ++j) { a0[j] = 0.f; a1[j] = 0.f; }

#pragma unroll
        for (int kq = 0; kq < 8; ++kq) {
            float4 x0 = r0[kq];
            float4 x1 = r1[kq];
#pragma unroll
            for (int kk = 0; kk < 4; ++kk) {
                int k = kq * 4 + kk;
                float xa = (kk == 0) ? x0.x : (kk == 1) ? x0.y : (kk == 2) ? x0.z : x0.w;
                float xb = (kk == 0) ? x1.x : (kk == 1) ? x1.y : (kk == 2) ? x1.z : x1.w;
#pragma unroll
                for (int j = 0; j < 32; ++j) {
                    float w = We[k * 32 + j];   // lane-uniform -> s_load
                    a0[j] = fmaf(xa, w, a0[j]);
                    a1[j] = fmaf(xb, w, a1[j]);
                }
            }
        }
        {
            float4 ev0 = *(const float4*)(ef_t + (size_t)p * 4);
            float4 ev1 = has2 ? *(const float4*)(ef_t + (size_t)(p + 1) * 4) : ev0;
#pragma unroll
            for (int kk = 0; kk < 4; ++kk) {
                int k = 32 + kk;
                float xa = (kk == 0) ? ev0.x : (kk == 1) ? ev0.y : (kk == 2) ? ev0.z : ev0.w;
                float xb = (kk == 0) ? ev1.x : (kk == 1) ? ev1.y : (kk == 2) ? ev1.z : ev1.w;
#pragma unroll
                for (int j = 0; j < 32; ++j) {
                    float w = We[k * 32 + j];
                    a0[j] = fmaf(xa, w, a0[j]);
                    a1[j] = fmaf(xb, w, a1[j]);
                }
            }
        }
        // relu + combine same-dst pair, then LDS atomic flush
        if (d1 == d0) {
            int dl = d0 - nb0;
#pragma unroll
            for (int j = 0; j < 32; ++j)
                atomicAdd(&sagg[dl * 33 + j], fmaxf(a0[j], 0.f) + fmaxf(a1[j], 0.f));
        } else {
            int dl0 = d0 - nb0;
#pragma unroll
            for (int j = 0; j < 32; ++j)
                atomicAdd(&sagg[dl0 * 33 + j], fmaxf(a0[j], 0.f));
            if (d1 >= 0) {
                int dl1 = d1 - nb0;
#pragma unroll
                for (int j = 0; j < 32; ++j)
                    atomicAdd(&sagg[dl1 * 33 + j], fmaxf(a1[j], 0.f));
            }
        }
    }
    __syncthreads();

    // -------- node phase: 8-way k-split --------
    int nl = tid & 31;
    int q8 = tid >> 5;          // 0..7
    int n = nb0 + nl;
    bool on = (nl < nloc);
    float acc[32];
#pragma unroll
    for (int j = 0; j < 32; ++j) acc[j] = 0.f;
    if (on) {
        int k0 = q8 * 8;
#pragma unroll
        for (int kk = 0; kk < 8; ++kk) {
            int k = k0 + kk;
            float xk = (k < 32) ? shl[nl * 33 + k] : sagg[nl * 33 + (k - 32)];
            const float4* wr = (const float4*)(Wn + (size_t)k * 32);
#pragma unroll
            for (int j4 = 0; j4 < 8; ++j4) {
                float4 w = wr[j4];
                acc[4 * j4 + 0] = fmaf(xk, w.x, acc[4 * j4 + 0]);
                acc[4 * j4 + 1] = fmaf(xk, w.y, acc[4 * j4 + 1]);
                acc[4 * j4 + 2] = fmaf(xk, w.z, acc[4 * j4 + 2]);
                acc[4 * j4 + 3] = fmaf(xk, w.w, acc[4 * j4 + 3]);
            }
        }
        if (q8 == 7) {
            float rain = rain0[(size_t)n * T_STEPS + t];
            const float4* wr = (const float4*)(Wn + (size_t)64 * 32);
#pragma unroll
            for (int j4 = 0; j4 < 8; ++j4) {
                float4 w = wr[j4];
                acc[4 * j4 + 0] = fmaf(rain, w.x, acc[4 * j4 + 0]);
                acc[4 * j4 + 1] = fmaf(rain, w.y, acc[4 * j4 + 1]);
                acc[4 * j4 + 2] = fmaf(rain, w.z, acc[4 * j4 + 2]);
                acc[4 * j4 + 3] = fmaf(rain, w.w, acc[4 * j4 + 3]);
            }
        }
    }
    __syncthreads();
    // reuse shl as output accumulator
    for (int i = tid; i < NPB * 33; i += 256) shl[i] = 0.f;
    __syncthreads();
    if (on) {
#pragma unroll
        for (int j = 0; j < 32; ++j) atomicAdd(&shl[nl * 33 + j], acc[j]);
    }
    __syncthreads();
    if (tid < nloc) {
        int nn = nb0 + tid;
        float r = 0.f;
        float4* hw = (float4*)(hnew + (size_t)nn * H);
#pragma unroll
        for (int j4 = 0; j4 < 8; ++j4) {
            float4 v;
            v.x = fmaxf(shl[tid * 33 + 4 * j4 + 0], 0.f);
            v.y = fmaxf(shl[tid * 33 + 4 * j4 + 1], 0.f);
            v.z = fmaxf(shl[tid * 33 + 4 * j4 + 2], 0.f);
            v.w = fmaxf(shl[tid * 33 + 4 * j4 + 3], 0.f);
            hw[j4] = v;
            float4 wr = *(const float4*)(Wrain + 4 * j4);
            r += v.x * wr.x + v.y * wr.y + v.z * wr.z + v.w * wr.w;
        }
        if (last) out[(size_t)nn * T_STEPS + t] = r;
    }
}

extern "C" void kernel_launch(void* const* d_in, const int* in_sizes, int n_in,
                              void* d_out, int out_size, void* d_ws, size_t ws_size,
                              hipStream_t stream) {
    const float* inputs     = (const float*)d_in[0];
    const float* e_feats    = (const float*)d_in[1];
    const float* rain0      = (const float*)d_in[2];
    const float* W_emb      = (const float*)d_in[3];
    const float* W_edge_in  = (const float*)d_in[4];
    const float* W_node_in  = (const float*)d_in[5];
    const float* W_edge_out = (const float*)d_in[6];
    const float* W_node_out = (const float*)d_in[7];
    const float* W_rain     = (const float*)d_in[8];
    const int*   src        = (const int*)d_in[9];
    const int*   dst        = (const int*)d_in[10];
    float* out = (float*)d_out;

    // workspace layout (~74 MB)
    size_t fH = (size_t)NN * H;
    size_t fE = (size_t)NE * 4;
    float* h_a       = (float*)d_ws;
    float* h_b       = h_a + fH;
    float* ef_sorted = h_b + fH;                                   // T * NE * 4 floats
    int* row_ptr     = (int*)(ef_sorted + (size_t)T_STEPS * fE);   // NN+1
    int* deg         = row_ptr + (NN + 1);                         // NN
    int* cnt         = deg + NN;                                   // NN
    int* src_sorted  = cnt + NN;                                   // NE
    int* dst_sorted  = src_sorted + NE;                            // NE
    int* eid_sorted  = dst_sorted + NE;                            // NE

    embed_kernel<<<(NN * H + 255) / 256, 256, 0, stream>>>(inputs, W_emb, h_a);

    // CSR build
    hipMemsetAsync(deg, 0, (size_t)2 * NN * sizeof(int), stream);  // deg + cnt contiguous
    hist_kernel<<<(NE + 255) / 256, 256, 0, stream>>>(dst, deg);
    scan_kernel<<<1, 1024, 0, stream>>>(deg, row_ptr);
    scatter_kernel<<<(NE + 255) / 256, 256, 0, stream>>>(src, dst, row_ptr, cnt,
                                                         src_sorted, dst_sorted, eid_sorted);
    ef_sort_kernel<<<(NE + 255) / 256, 256, 0, stream>>>(e_feats, eid_sorted, ef_sorted);

    float* hc = h_a;
    float* hn = h_b;
    for (int t = 0; t < T_STEPS; ++t) {
        const float* ef_t = ef_sorted + (size_t)t * fE;
        for (int s = 0; s < 3; ++s) {
            const float* We = (s < 2) ? (W_edge_in + (size_t)s * 36 * H) : W_edge_out;
            const float* Wn = (s < 2) ? (W_node_in + (size_t)s * 65 * H) : W_node_out;
            layer_kernel<<<NBLK, 256, 0, stream>>>(hc, ef_t, src_sorted, dst_sorted, row_ptr, rain0,
                                                   We, Wn, W_rain, hn, out, t, (s == 2) ? 1 : 0);
            float* tmp = hc; hc = hn; hn = tmp;
        }
    }
}